// Round 13
// baseline (257.599 us; speedup 1.0000x reference)
//
#include <hip/hip_runtime.h>
#include <hip/hip_fp16.h>
#include <math.h>

#define NEG_SLOPE 0.2f
#define LOG2E 1.44269504088896f

#if __has_builtin(__builtin_amdgcn_exp2f)
#define EXP2(x) __builtin_amdgcn_exp2f(x)
#else
#define EXP2(x) exp2f(x)
#endif

typedef _Float16 half8 __attribute__((ext_vector_type(8)));
typedef float floatx4 __attribute__((ext_vector_type(4)));

// ---------------- L1: pack W1 (blocks 0..15) + zero deg[N]+binCnt+cursor -----------
// zbuf layout: deg[N] ++ binCnt[256*16 padded] ++ cursor[256*16 padded]
__global__ __launch_bounds__(256) void prep1(const float* __restrict__ W1,
                                             half8* __restrict__ Bpack,
                                             int* __restrict__ zbuf, int N) {
  if (blockIdx.x < 16) {
    int tid = blockIdx.x * 256 + threadIdx.x;  // 4096 total
    int l = tid & 63;
    int ksnt = tid >> 6;
    int ks = ksnt & 3;
    int nt = ksnt >> 2;
    int col = nt * 16 + (l & 15);
    int krow = ks * 32 + (l >> 4) * 8;
    half8 v;
#pragma unroll
    for (int j = 0; j < 8; j++) v[j] = (_Float16)W1[(krow + j) * 256 + col];
    Bpack[tid] = v;
  } else {
    int i = (blockIdx.x - 16) * 256 + threadIdx.x;
    if (i < N + 8192) zbuf[i] = 0;
  }
}

// ---------------- L2: gemm1 MFMA -> per-head int8 slices + per-head meta ∥ hist ----
// h1qh layout: [head][node][64] bytes (3.2MB per head slice).
// a1h layout:  [head][node] float2 {a1s_h*log2e, hscale}.
__global__ __launch_bounds__(256) void phase2(
    const float* __restrict__ x, const half8* __restrict__ Bpack,
    const float* __restrict__ att_s, const float* __restrict__ att_d,
    unsigned char* __restrict__ h1qh, float2* __restrict__ a1h,
    float* __restrict__ a1d,
    const int* __restrict__ dst, int* __restrict__ deg, int* __restrict__ rank,
    int N, int E, int gemmBlocks, int histBlocks) {
  if ((int)blockIdx.x >= gemmBlocks) {
    int b = blockIdx.x - gemmBlocks;
    for (int e = b * 256 + threadIdx.x; e < E; e += histBlocks * 256)
      rank[e] = atomicAdd(deg + dst[e], 1);
    return;
  }
  const int wave = threadIdx.x >> 6, lane = threadIdx.x & 63;
  const int quad = lane >> 4, li = lane & 15;
  const int n0 = (blockIdx.x * 4 + wave) * 16;
  if (n0 >= N) return;
  const size_t N64 = (size_t)N * 64;
  floatx4 acc[16];
#pragma unroll
  for (int t = 0; t < 16; t++) acc[t] = (floatx4){0.f, 0.f, 0.f, 0.f};
  const float* xrow = x + (size_t)(n0 + li) * 128;
#pragma unroll
  for (int ks = 0; ks < 4; ks++) {
    float4 xa = *(const float4*)(xrow + ks * 32 + quad * 8);
    float4 xb = *(const float4*)(xrow + ks * 32 + quad * 8 + 4);
    half8 a;
    a[0] = (_Float16)xa.x; a[1] = (_Float16)xa.y;
    a[2] = (_Float16)xa.z; a[3] = (_Float16)xa.w;
    a[4] = (_Float16)xb.x; a[5] = (_Float16)xb.y;
    a[6] = (_Float16)xb.z; a[7] = (_Float16)xb.w;
#pragma unroll
    for (int nt = 0; nt < 16; nt++) {
      half8 b = Bpack[(nt * 4 + ks) * 64 + lane];
      acc[nt] = __builtin_amdgcn_mfma_f32_16x16x32_f16(a, b, acc[nt], 0, 0, 0);
    }
  }
  // int8 quantize: row (m = quad*4 + r) absmax over 256 ch -> scale
  float scv[4];
#pragma unroll
  for (int r = 0; r < 4; r++) {
    float m = 0.f;
#pragma unroll
    for (int nt = 0; nt < 16; nt++) m = fmaxf(m, fabsf(acc[nt][r]));
#pragma unroll
    for (int off = 8; off > 0; off >>= 1) m = fmaxf(m, __shfl_xor(m, off, 16));
    m = fmaxf(m, 1e-8f);
    float inv = 127.0f / m;
    scv[r] = m * (1.0f / 127.0f);
    int node = n0 + quad * 4 + r;
#pragma unroll
    for (int nt = 0; nt < 16; nt++) {
      h1qh[(size_t)(nt >> 2) * N64 + (size_t)node * 64 + (nt & 3) * 16 + li] =
          (unsigned char)(int)(fmaf(acc[nt][r], inv, 128.5f));
    }
  }
  // fused attention dots (fp32 acc, pre-quantization), pre-scaled by log2e
  float as_f[16], ad_f[16];
#pragma unroll
  for (int nt = 0; nt < 16; nt++) {
    as_f[nt] = att_s[nt * 16 + li];
    ad_f[nt] = att_d[nt * 16 + li];
  }
#pragma unroll
  for (int r = 0; r < 4; r++) {
    int node = n0 + quad * 4 + r;
#pragma unroll
    for (int h = 0; h < 4; h++) {
      float vs = 0.f, vd = 0.f;
#pragma unroll
      for (int ntl = 0; ntl < 4; ntl++) {
        int nt = h * 4 + ntl;
        vs = fmaf(acc[nt][r], as_f[nt], vs);
        vd = fmaf(acc[nt][r], ad_f[nt], vd);
      }
#pragma unroll
      for (int off = 8; off > 0; off >>= 1) {
        vs += __shfl_down(vs, off, 16);
        vd += __shfl_down(vd, off, 16);
      }
      if (li == 0) {
        a1h[(size_t)h * N + node] = make_float2(vs * LOG2E, scv[r]);
        a1d[node * 4 + h] = vd * LOG2E;
      }
    }
  }
}

// ---------------- CSR scan chain + folded LDS degree histogram ----------------
__global__ void scan_local(const int* __restrict__ deg, int* __restrict__ excl,
                           int* __restrict__ bsum, int* __restrict__ binCnt, int N) {
  __shared__ int s[256];
  __shared__ int hh[256];
  hh[threadIdx.x] = 0;
  int i = blockIdx.x * 256 + threadIdx.x;
  int d = (i < N) ? deg[i] : -1;
  int v = (i < N) ? d + 1 : 0;  // +1 self-loop
  s[threadIdx.x] = v;
  __syncthreads();
  if (d >= 0) atomicAdd(&hh[min(d, 255)], 1);
  for (int off = 1; off < 256; off <<= 1) {
    int t = (threadIdx.x >= off) ? s[threadIdx.x - off] : 0;
    __syncthreads();
    s[threadIdx.x] += t;
    __syncthreads();
  }
  if (i < N) excl[i] = s[threadIdx.x] - v;
  if (threadIdx.x == 255) bsum[blockIdx.x] = s[255];
  __syncthreads();
  if (hh[threadIdx.x] > 0) atomicAdd(binCnt + threadIdx.x * 16, hh[threadIdx.x]);
}

// scan_add2 (blocks 0..nb-1) + folded binscan (block nb): binCnt was finalized in
// the previous launch; block nb computes the exclusive bin scan -> cursor.
__global__ void scan_add2(const int* __restrict__ excl, const int* __restrict__ bsum,
                          const int* __restrict__ binCnt, int* __restrict__ cursor,
                          int* __restrict__ rowptr, unsigned short* __restrict__ elist,
                          int N, int nb) {
  __shared__ int s[256];
  if ((int)blockIdx.x == nb) {  // folded binscan
    int v = binCnt[threadIdx.x * 16];
    s[threadIdx.x] = v;
    __syncthreads();
    for (int off = 1; off < 256; off <<= 1) {
      int t = (threadIdx.x >= off) ? s[threadIdx.x - off] : 0;
      __syncthreads();
      s[threadIdx.x] += t;
      __syncthreads();
    }
    cursor[threadIdx.x * 16] = s[threadIdx.x] - v;
    return;
  }
  int v = (threadIdx.x < nb) ? bsum[threadIdx.x] : 0;
  s[threadIdx.x] = v;
  __syncthreads();
  for (int off = 1; off < 256; off <<= 1) {
    int t = (threadIdx.x >= off) ? s[threadIdx.x - off] : 0;
    __syncthreads();
    s[threadIdx.x] += t;
    __syncthreads();
  }
  __syncthreads();
  int base = (blockIdx.x > 0) ? s[blockIdx.x - 1] : 0;  // exclusive block offset
  int i = blockIdx.x * 256 + threadIdx.x;
  if (i < N) {
    int r = excl[i] + base;
    rowptr[i] = r;
    elist[r] = (unsigned short)i;  // self-loop first
  }
  if (blockIdx.x == 0 && threadIdx.x == 0) rowptr[N] = s[nb - 1];  // total = ET
}

// ---------------- merged: scatter2 (blocks < scatB) ∥ place+mkdesc (rest) ---------
__global__ __launch_bounds__(256) void scatter_place(
    const int* __restrict__ src, const int* __restrict__ dst,
    const int* __restrict__ rank, const int* __restrict__ rowptr,
    const int* __restrict__ deg, int* __restrict__ cursor,
    unsigned short* __restrict__ elist, int2* __restrict__ ndesc,
    int E, int N, int scatB) {
  if ((int)blockIdx.x < scatB) {
    int e = blockIdx.x * 256 + threadIdx.x;
    if (e >= E) return;
    elist[rowptr[dst[e]] + 1 + rank[e]] = (unsigned short)src[e];
    return;
  }
  __shared__ int h[256];
  __shared__ int base[256];
  h[threadIdx.x] = 0;
  __syncthreads();
  int i = (blockIdx.x - scatB) * 256 + threadIdx.x;
  int b = 0, lr = 0;
  bool a = i < N;
  int d = 0;
  if (a) {
    d = deg[i];
    b = min(d, 255);
    lr = atomicAdd(&h[b], 1);
  }
  __syncthreads();
  if (h[threadIdx.x] > 0)
    base[threadIdx.x] = atomicAdd(cursor + threadIdx.x * 16, h[threadIdx.x]);
  __syncthreads();
  if (a) ndesc[base[b] + lr] = make_int2(rowptr[i], ((d + 1) << 16) | i);
}

// ---------------- agg1_heads: per-head spatially XCD-sliced aggregation.
// head = (blockIdx%8)>>1  ->  each XCD pair works ONE 3.2MB h1q slice + 0.4MB meta
// (fits 4MB L2). Wave = 8 nodes x 8 lanes (8 int8 ch/lane, uint2 = 1 line/edge).
// ndesc read REVERSED (heavy nodes first; straggler fix). R13: edge loop unroll
// 4 -> 8 (24 loads in flight per 8-lane group) — MLP retest in the L2-resident
// regime (R1's null was the HBM-random regime). Per-node summation order is
// unchanged (u=0..7 sequential) -> bit-identical results. -------------------------
__global__ __launch_bounds__(256) void agg1_heads(
    const int2* __restrict__ ndesc, const unsigned short* __restrict__ elist,
    const unsigned char* __restrict__ h1qh, const float2* __restrict__ a1h,
    const float* __restrict__ a1d, const float* __restrict__ b1,
    const float* __restrict__ W2, float* __restrict__ phuf, int N) {
  __shared__ float w2s[256 * 11];  // stride 11 -> conflict-light
  const int t = threadIdx.x;
  for (int i = t; i < 2560; i += 256) {
    int ch = i / 10, jj = i - ch * 10;
    w2s[ch * 11 + jj] = W2[i];
  }

  const int wave = t >> 6, lane = t & 63;
  const int s = lane >> 3;              // node slot in wave: 0..7
  const int k = lane & 7;               // 8 ch per lane: ch = k*8..k*8+7 (in-head)
  const int xcd = blockIdx.x & 7;
  const int head = xcd >> 1, sub = xcd & 1;
  const int chunk = (blockIdx.x >> 3) * 2 + sub;
  const int gidx = chunk * 32 + wave * 8 + s;
  const bool act = gidx < N;
  int2 nd = act ? ndesc[N - 1 - gidx] : make_int2(0, 0);
  const int n = nd.y & 0xFFFF;
  const int row = nd.x;
  const int en = row + (nd.y >> 16);        // includes self-loop
  const float adh = act ? a1d[n * 4 + head] : 0.f;
  const float2* mh = a1h + (size_t)head * N;
  const unsigned char* hb = h1qh + (size_t)head * N * 64 + k * 8;

  float den = 0.f, T = 0.f;
  float acc[8];
#pragma unroll
  for (int u = 0; u < 8; u++) acc[u] = 0.f;

#define EDGEMAC(SEV, AV, BV)                                        \
  do {                                                              \
    float _se = (SEV);                                              \
    unsigned _a = (AV), _b = (BV);                                  \
    acc[0] = fmaf((float)(_a & 0xffu), _se, acc[0]);                \
    acc[1] = fmaf((float)((_a >> 8) & 0xffu), _se, acc[1]);         \
    acc[2] = fmaf((float)((_a >> 16) & 0xffu), _se, acc[2]);        \
    acc[3] = fmaf((float)(_a >> 24), _se, acc[3]);                  \
    acc[4] = fmaf((float)(_b & 0xffu), _se, acc[4]);                \
    acc[5] = fmaf((float)((_b >> 8) & 0xffu), _se, acc[5]);         \
    acc[6] = fmaf((float)((_b >> 16) & 0xffu), _se, acc[6]);        \
    acc[7] = fmaf((float)(_b >> 24), _se, acc[7]);                  \
  } while (0)

  int j = row;
  for (; j + 8 <= en; j += 8) {
    int ss[8];
    float2 mv[8];
    uint2 qv[8];
#pragma unroll
    for (int u = 0; u < 8; u++) ss[u] = elist[j + u];
#pragma unroll
    for (int u = 0; u < 8; u++) {
      mv[u] = mh[ss[u]];
      qv[u] = *(const uint2*)(hb + ((size_t)ss[u] << 6));
    }
#pragma unroll
    for (int u = 0; u < 8; u++) {
      float l = mv[u].x + adh;
      float e = EXP2(fmaxf(l, NEG_SLOPE * l));
      den += e;
      float se = e * mv[u].y;
      T += se;
      EDGEMAC(se, qv[u].x, qv[u].y);
    }
  }
  for (; j + 4 <= en; j += 4) {
    int ss[4];
    float2 mv[4];
    uint2 qv[4];
#pragma unroll
    for (int u = 0; u < 4; u++) ss[u] = elist[j + u];
#pragma unroll
    for (int u = 0; u < 4; u++) {
      mv[u] = mh[ss[u]];
      qv[u] = *(const uint2*)(hb + ((size_t)ss[u] << 6));
    }
#pragma unroll
    for (int u = 0; u < 4; u++) {
      float l = mv[u].x + adh;
      float e = EXP2(fmaxf(l, NEG_SLOPE * l));
      den += e;
      float se = e * mv[u].y;
      T += se;
      EDGEMAC(se, qv[u].x, qv[u].y);
    }
  }
  for (; j < en; j++) {
    int s0 = elist[j];
    float2 mv = mh[s0];
    uint2 q0 = *(const uint2*)(hb + ((size_t)s0 << 6));
    float l0 = mv.x + adh;
    float e0 = EXP2(fmaxf(l0, NEG_SLOPE * l0));
    den += e0;
    float se = e0 * mv.y;
    T += se;
    EDGEMAC(se, q0.x, q0.y);
  }
#undef EDGEMAC

  __syncthreads();  // w2s ready (no thread returned early)

  // epilogue: normalize, +bias, ELU, partial GEMM2 over this head's 64 channels
  float bbv[8];
  {
    float4 b0 = *(const float4*)(b1 + head * 64 + k * 8);
    float4 b1v = *(const float4*)(b1 + head * 64 + k * 8 + 4);
    bbv[0] = b0.x; bbv[1] = b0.y; bbv[2] = b0.z; bbv[3] = b0.w;
    bbv[4] = b1v.x; bbv[5] = b1v.y; bbv[6] = b1v.z; bbv[7] = b1v.w;
  }
  float inv = act ? 1.0f / den : 0.f;
  float corr = 128.0f * T;
  float pv[10];
#pragma unroll
  for (int jj = 0; jj < 10; jj++) pv[jj] = 0.f;
#pragma unroll
  for (int u = 0; u < 8; u++) {
    float c = (acc[u] - corr) * inv + bbv[u];
    c = c > 0.f ? c : expm1f(c);
    const float* wrow = w2s + (head * 64 + k * 8 + u) * 11;
#pragma unroll
    for (int jj = 0; jj < 10; jj++) pv[jj] = fmaf(c, wrow[jj], pv[jj]);
  }
#pragma unroll
  for (int off = 4; off > 0; off >>= 1) {
#pragma unroll
    for (int jj = 0; jj < 10; jj++) pv[jj] += __shfl_down(pv[jj], off, 8);
  }
  if (act && k == 0) {
    float* pp = phuf + ((size_t)n * 4 + head) * 10;
#pragma unroll
    for (int jj = 0; jj < 10; jj++) pp[jj] = pv[jj];
  }
}

// ---------------- combine: sum 4 head-partials -> h2 (fp16) + att2 tails ----------
__global__ __launch_bounds__(256) void combine(
    const float* __restrict__ phuf, const float* __restrict__ as2,
    const float* __restrict__ ad2, __half* __restrict__ h2, int N) {
  int n = blockIdx.x * 256 + threadIdx.x;
  if (n >= N) return;
  const float* pp = phuf + (size_t)n * 40;
  float ds = 0.f, dd = 0.f;
#pragma unroll
  for (int jj = 0; jj < 10; jj++) {
    float p = pp[jj] + pp[10 + jj] + pp[20 + jj] + pp[30 + jj];
    h2[(size_t)n * 16 + jj] = __float2half(p);
    ds = fmaf(p, as2[jj], ds);
    dd = fmaf(p, ad2[jj], dd);
  }
  float* ft = (float*)(h2 + (size_t)n * 16);
  ft[5] = ds * LOG2E;   // a2s in h2 row tail
  ft[6] = dd * LOG2E;   // a2d
}

// ---------------- agg2: wave-per-node, 12 groups x 5 lanes (half2 = 2 channels).
// a2s/a2d read from the h2 row tail -> exactly ONE 64B line per edge; u16 elist. --
__global__ __launch_bounds__(256) void agg2_csr(
    const int* __restrict__ rowptr, const unsigned short* __restrict__ elist,
    const __half* __restrict__ h2, const float* __restrict__ b2,
    float* __restrict__ out, int N) {
  int wave = threadIdx.x >> 6, lane = threadIdx.x & 63;
  int n = blockIdx.x * 4 + wave;
  if (n >= N) return;
  int row = rowptr[n];
  int deg = rowptr[n + 1] - row;
  const unsigned short* el = elist + row;
  const float* hf = (const float*)h2;
  float ad = hf[(size_t)n * 8 + 6];  // pre-scaled a2d from own row tail
  int g = lane / 5;      // 0..11 active, lanes 60-63 idle (g=12)
  int c2 = lane - g * 5; // channel-pair index 0..4
  float den = 0.f, ax = 0.f, ay = 0.f;
  if (g < 12) {
    int jj = g;
    for (; jj + 12 < deg; jj += 24) {
      int sA = el[jj], sB = el[jj + 12];
      float lA = hf[(size_t)sA * 8 + 5] + ad;
      float lB = hf[(size_t)sB * 8 + 5] + ad;
      __half2 hA = *(const __half2*)(h2 + (size_t)sA * 16 + c2 * 2);
      __half2 hB = *(const __half2*)(h2 + (size_t)sB * 16 + c2 * 2);
      float eA = EXP2(fmaxf(lA, NEG_SLOPE * lA));
      float eB = EXP2(fmaxf(lB, NEG_SLOPE * lB));
      den += eA + eB;
      float2 fA = __half22float2(hA);
      float2 fB = __half22float2(hB);
      ax = fmaf(eA, fA.x, fmaf(eB, fB.x, ax));
      ay = fmaf(eA, fA.y, fmaf(eB, fB.y, ay));
    }
    for (; jj < deg; jj += 12) {
      int s = el[jj];
      float l = hf[(size_t)s * 8 + 5] + ad;
      __half2 hv = *(const __half2*)(h2 + (size_t)s * 16 + c2 * 2);
      float ev = EXP2(fmaxf(l, NEG_SLOPE * l));
      den += ev;
      float2 f = __half22float2(hv);
      ax = fmaf(ev, f.x, ax);
      ay = fmaf(ev, f.y, ay);
    }
  }
  // reduce the 12 stride-5 groups: +30 (g+6), then +10/+20 (g+2,g+4), then +5 (g+1)
  ax += __shfl_down(ax, 30, 64);
  ay += __shfl_down(ay, 30, 64);
  den += __shfl_down(den, 30, 64);
  ax += __shfl_down(ax, 10, 64) + __shfl_down(ax, 20, 64);
  ay += __shfl_down(ay, 10, 64) + __shfl_down(ay, 20, 64);
  den += __shfl_down(den, 10, 64) + __shfl_down(den, 20, 64);
  ax += __shfl_down(ax, 5, 64);
  ay += __shfl_down(ay, 5, 64);
  den += __shfl_down(den, 5, 64);
  if (lane < 5) {
    float inv = 1.0f / den;
    float2 bb = *(const float2*)(b2 + lane * 2);
    float2 o = make_float2(fmaf(ax, inv, bb.x), fmaf(ay, inv, bb.y));
    *(float2*)(out + (size_t)n * 10 + lane * 2) = o;
  }
}

extern "C" void kernel_launch(void* const* d_in, const int* in_sizes, int n_in,
                              void* d_out, int out_size, void* d_ws, size_t ws_size,
                              hipStream_t stream) {
  const float* x = (const float*)d_in[0];
  const int* ei = (const int*)d_in[1];
  const float* W1 = (const float*)d_in[2];
  const float* as1 = (const float*)d_in[3];
  const float* ad1 = (const float*)d_in[4];
  const float* b1 = (const float*)d_in[5];
  const float* W2 = (const float*)d_in[6];
  const float* as2 = (const float*)d_in[7];
  const float* ad2 = (const float*)d_in[8];
  const float* b2 = (const float*)d_in[9];
  float* out = (float*)d_out;

  const int N = in_sizes[0] / 128;   // 50000
  const int E = in_sizes[1] / 2;     // 800000
  const int* srcp = ei;
  const int* dstp = ei + E;

  char* ws = (char*)d_ws;
  size_t off = 0;
  auto alloc = [&](size_t nbytes) {
    char* p = ws + off;
    off += (nbytes + 255) & ~(size_t)255;
    return p;
  };
  unsigned char* h1qh = (unsigned char*)alloc((size_t)N * 256);  // [4][N][64]
  float2* a1h = (float2*)alloc((size_t)N * 4 * 8);               // [4][N]{a1s,hscale}
  half8* Bpack = (half8*)alloc((size_t)4096 * 16);
  float* a1d = (float*)alloc((size_t)N * 4 * 4);
  float* phuf = (float*)alloc((size_t)N * 40 * 4);               // [N][4][10]
  __half* h2 = (__half*)alloc((size_t)N * 16 * 2);
  int* zbuf = (int*)alloc((size_t)(N + 8192) * 4);  // deg[N] ++ binCnt pad ++ cursor pad
  int* deg = zbuf;
  int* binCnt = zbuf + N;          // [256] stride-16 (64B line each)
  int* cursor = zbuf + N + 4096;   // [256] stride-16
  int* excl = (int*)alloc((size_t)N * 4);
  int* bsum = (int*)alloc(256 * 4);
  int* rowptr = (int*)alloc((size_t)(N + 1) * 4);
  int2* ndesc = (int2*)alloc((size_t)N * 8);
  int* rank = (int*)alloc((size_t)E * 4);
  unsigned short* elist = (unsigned short*)alloc((size_t)(E + (size_t)N) * 2);

  const int nb = (N + 255) / 256;          // 196
  const int nbz = (N + 8192 + 255) / 256;
  const int gemmBlocks = (N / 16 + 3) / 4; // 782
  const int histBlocks = 512;
  const int scatB = (E + 255) / 256;       // 3125
  const int chunks = (N + 31) / 32;        // 1563 (32 nodes per block per head)
  const int hgrid = ((chunks + 1) / 2) * 8;

  // L1: pack W1 + zero deg/binCnt/cursor
  prep1<<<16 + nbz, 256, 0, stream>>>(W1, Bpack, zbuf, N);
  // L2: gemm1 (MFMA -> per-head int8 slices + per-head meta, att dots) || hist+rank
  phase2<<<gemmBlocks + histBlocks, 256, 0, stream>>>(
      x, Bpack, as1, ad1, h1qh, a1h, a1d, dstp, deg, rank, N, E,
      gemmBlocks, histBlocks);
  // CSR: scan (+LDS deg-hist), then {rowptr+selfloops ∥ binscan}, then
  // {scatter ∥ place+ndesc} — 3 launches total for the whole CSR/sort chain
  scan_local<<<nb, 256, 0, stream>>>(deg, excl, bsum, binCnt, N);
  scan_add2<<<nb + 1, 256, 0, stream>>>(excl, bsum, binCnt, cursor, rowptr, elist,
                                        N, nb);
  scatter_place<<<scatB + nb, 256, 0, stream>>>(srcp, dstp, rank, rowptr, deg,
                                                cursor, elist, ndesc, E, N, scatB);
  // layer 1 aggregate, head-sliced per XCD pair (+ per-head partial GEMM2)
  agg1_heads<<<hgrid, 256, 0, stream>>>(ndesc, elist, h1qh, a1h, a1d,
                                        b1, W2, phuf, N);
  // sum head partials -> h2 + att2 tails
  combine<<<(N + 255) / 256, 256, 0, stream>>>(phuf, as2, ad2, h2, N);
  // layer 2 aggregate
  agg2_csr<<<(N + 3) / 4, 256, 0, stream>>>(rowptr, elist, h2, b2, out, N);
}

// Round 14
// 243.062 us; speedup vs baseline: 1.0598x; 1.0598x over previous
//
#include <hip/hip_runtime.h>
#include <hip/hip_fp16.h>
#include <math.h>

#define NEG_SLOPE 0.2f
#define LOG2E 1.44269504088896f

#if __has_builtin(__builtin_amdgcn_exp2f)
#define EXP2(x) __builtin_amdgcn_exp2f(x)
#else
#define EXP2(x) exp2f(x)
#endif

typedef _Float16 half8 __attribute__((ext_vector_type(8)));
typedef float floatx4 __attribute__((ext_vector_type(4)));

// ---------------- L1: pack W1 (blocks 0..15) + zero deg[N]+binCnt+cursor -----------
// zbuf layout: deg[N] ++ binCnt[256*16 padded] ++ cursor[256*16 padded]
__global__ __launch_bounds__(256) void prep1(const float* __restrict__ W1,
                                             half8* __restrict__ Bpack,
                                             int* __restrict__ zbuf, int N) {
  if (blockIdx.x < 16) {
    int tid = blockIdx.x * 256 + threadIdx.x;  // 4096 total
    int l = tid & 63;
    int ksnt = tid >> 6;
    int ks = ksnt & 3;
    int nt = ksnt >> 2;
    int col = nt * 16 + (l & 15);
    int krow = ks * 32 + (l >> 4) * 8;
    half8 v;
#pragma unroll
    for (int j = 0; j < 8; j++) v[j] = (_Float16)W1[(krow + j) * 256 + col];
    Bpack[tid] = v;
  } else {
    int i = (blockIdx.x - 16) * 256 + threadIdx.x;
    if (i < N + 8192) zbuf[i] = 0;
  }
}

// ---------------- L2: gemm1 MFMA -> per-head int8 slices + per-head meta ∥ hist ----
// h1qh layout: [head][node][64] bytes (3.2MB per head slice).
// a1h layout:  [head][node] float2 {a1s_h*log2e, hscale}.
__global__ __launch_bounds__(256) void phase2(
    const float* __restrict__ x, const half8* __restrict__ Bpack,
    const float* __restrict__ att_s, const float* __restrict__ att_d,
    unsigned char* __restrict__ h1qh, float2* __restrict__ a1h,
    float* __restrict__ a1d,
    const int* __restrict__ dst, int* __restrict__ deg, int* __restrict__ rank,
    int N, int E, int gemmBlocks, int histBlocks) {
  if ((int)blockIdx.x >= gemmBlocks) {
    int b = blockIdx.x - gemmBlocks;
    for (int e = b * 256 + threadIdx.x; e < E; e += histBlocks * 256)
      rank[e] = atomicAdd(deg + dst[e], 1);
    return;
  }
  const int wave = threadIdx.x >> 6, lane = threadIdx.x & 63;
  const int quad = lane >> 4, li = lane & 15;
  const int n0 = (blockIdx.x * 4 + wave) * 16;
  if (n0 >= N) return;
  const size_t N64 = (size_t)N * 64;
  floatx4 acc[16];
#pragma unroll
  for (int t = 0; t < 16; t++) acc[t] = (floatx4){0.f, 0.f, 0.f, 0.f};
  const float* xrow = x + (size_t)(n0 + li) * 128;
#pragma unroll
  for (int ks = 0; ks < 4; ks++) {
    float4 xa = *(const float4*)(xrow + ks * 32 + quad * 8);
    float4 xb = *(const float4*)(xrow + ks * 32 + quad * 8 + 4);
    half8 a;
    a[0] = (_Float16)xa.x; a[1] = (_Float16)xa.y;
    a[2] = (_Float16)xa.z; a[3] = (_Float16)xa.w;
    a[4] = (_Float16)xb.x; a[5] = (_Float16)xb.y;
    a[6] = (_Float16)xb.z; a[7] = (_Float16)xb.w;
#pragma unroll
    for (int nt = 0; nt < 16; nt++) {
      half8 b = Bpack[(nt * 4 + ks) * 64 + lane];
      acc[nt] = __builtin_amdgcn_mfma_f32_16x16x32_f16(a, b, acc[nt], 0, 0, 0);
    }
  }
  // int8 quantize: row (m = quad*4 + r) absmax over 256 ch -> scale
  float scv[4];
#pragma unroll
  for (int r = 0; r < 4; r++) {
    float m = 0.f;
#pragma unroll
    for (int nt = 0; nt < 16; nt++) m = fmaxf(m, fabsf(acc[nt][r]));
#pragma unroll
    for (int off = 8; off > 0; off >>= 1) m = fmaxf(m, __shfl_xor(m, off, 16));
    m = fmaxf(m, 1e-8f);
    float inv = 127.0f / m;
    scv[r] = m * (1.0f / 127.0f);
    int node = n0 + quad * 4 + r;
#pragma unroll
    for (int nt = 0; nt < 16; nt++) {
      h1qh[(size_t)(nt >> 2) * N64 + (size_t)node * 64 + (nt & 3) * 16 + li] =
          (unsigned char)(int)(fmaf(acc[nt][r], inv, 128.5f));
    }
  }
  // fused attention dots (fp32 acc, pre-quantization), pre-scaled by log2e
  float as_f[16], ad_f[16];
#pragma unroll
  for (int nt = 0; nt < 16; nt++) {
    as_f[nt] = att_s[nt * 16 + li];
    ad_f[nt] = att_d[nt * 16 + li];
  }
#pragma unroll
  for (int r = 0; r < 4; r++) {
    int node = n0 + quad * 4 + r;
#pragma unroll
    for (int h = 0; h < 4; h++) {
      float vs = 0.f, vd = 0.f;
#pragma unroll
      for (int ntl = 0; ntl < 4; ntl++) {
        int nt = h * 4 + ntl;
        vs = fmaf(acc[nt][r], as_f[nt], vs);
        vd = fmaf(acc[nt][r], ad_f[nt], vd);
      }
#pragma unroll
      for (int off = 8; off > 0; off >>= 1) {
        vs += __shfl_down(vs, off, 16);
        vd += __shfl_down(vd, off, 16);
      }
      if (li == 0) {
        a1h[(size_t)h * N + node] = make_float2(vs * LOG2E, scv[r]);
        a1d[node * 4 + h] = vd * LOG2E;
      }
    }
  }
}

// ---------------- CSR scan chain + folded LDS degree histogram ----------------
__global__ void scan_local(const int* __restrict__ deg, int* __restrict__ excl,
                           int* __restrict__ bsum, int* __restrict__ binCnt, int N) {
  __shared__ int s[256];
  __shared__ int hh[256];
  hh[threadIdx.x] = 0;
  int i = blockIdx.x * 256 + threadIdx.x;
  int d = (i < N) ? deg[i] : -1;
  int v = (i < N) ? d + 1 : 0;  // +1 self-loop
  s[threadIdx.x] = v;
  __syncthreads();
  if (d >= 0) atomicAdd(&hh[min(d, 255)], 1);
  for (int off = 1; off < 256; off <<= 1) {
    int t = (threadIdx.x >= off) ? s[threadIdx.x - off] : 0;
    __syncthreads();
    s[threadIdx.x] += t;
    __syncthreads();
  }
  if (i < N) excl[i] = s[threadIdx.x] - v;
  if (threadIdx.x == 255) bsum[blockIdx.x] = s[255];
  __syncthreads();
  if (hh[threadIdx.x] > 0) atomicAdd(binCnt + threadIdx.x * 16, hh[threadIdx.x]);
}

// scan_add2 (blocks 0..nb-1) + folded binscan (block nb): binCnt was finalized in
// the previous launch; block nb computes the exclusive bin scan -> cursor.
__global__ void scan_add2(const int* __restrict__ excl, const int* __restrict__ bsum,
                          const int* __restrict__ binCnt, int* __restrict__ cursor,
                          int* __restrict__ rowptr, unsigned short* __restrict__ elist,
                          int N, int nb) {
  __shared__ int s[256];
  if ((int)blockIdx.x == nb) {  // folded binscan
    int v = binCnt[threadIdx.x * 16];
    s[threadIdx.x] = v;
    __syncthreads();
    for (int off = 1; off < 256; off <<= 1) {
      int t = (threadIdx.x >= off) ? s[threadIdx.x - off] : 0;
      __syncthreads();
      s[threadIdx.x] += t;
      __syncthreads();
    }
    cursor[threadIdx.x * 16] = s[threadIdx.x] - v;
    return;
  }
  int v = (threadIdx.x < nb) ? bsum[threadIdx.x] : 0;
  s[threadIdx.x] = v;
  __syncthreads();
  for (int off = 1; off < 256; off <<= 1) {
    int t = (threadIdx.x >= off) ? s[threadIdx.x - off] : 0;
    __syncthreads();
    s[threadIdx.x] += t;
    __syncthreads();
  }
  __syncthreads();
  int base = (blockIdx.x > 0) ? s[blockIdx.x - 1] : 0;  // exclusive block offset
  int i = blockIdx.x * 256 + threadIdx.x;
  if (i < N) {
    int r = excl[i] + base;
    rowptr[i] = r;
    elist[r] = (unsigned short)i;  // self-loop first
  }
  if (blockIdx.x == 0 && threadIdx.x == 0) rowptr[N] = s[nb - 1];  // total = ET
}

// ---------------- merged: scatter2 (blocks < scatB) ∥ place+mkdesc (rest) ---------
__global__ __launch_bounds__(256) void scatter_place(
    const int* __restrict__ src, const int* __restrict__ dst,
    const int* __restrict__ rank, const int* __restrict__ rowptr,
    const int* __restrict__ deg, int* __restrict__ cursor,
    unsigned short* __restrict__ elist, int2* __restrict__ ndesc,
    int E, int N, int scatB) {
  if ((int)blockIdx.x < scatB) {
    int e = blockIdx.x * 256 + threadIdx.x;
    if (e >= E) return;
    elist[rowptr[dst[e]] + 1 + rank[e]] = (unsigned short)src[e];
    return;
  }
  __shared__ int h[256];
  __shared__ int base[256];
  h[threadIdx.x] = 0;
  __syncthreads();
  int i = (blockIdx.x - scatB) * 256 + threadIdx.x;
  int b = 0, lr = 0;
  bool a = i < N;
  int d = 0;
  if (a) {
    d = deg[i];
    b = min(d, 255);
    lr = atomicAdd(&h[b], 1);
  }
  __syncthreads();
  if (h[threadIdx.x] > 0)
    base[threadIdx.x] = atomicAdd(cursor + threadIdx.x * 16, h[threadIdx.x]);
  __syncthreads();
  if (a) ndesc[base[b] + lr] = make_int2(rowptr[i], ((d + 1) << 16) | i);
}

// ---------------- agg1_heads: per-head spatially XCD-sliced aggregation.
// head = (blockIdx%8)>>1  ->  each XCD pair works ONE 3.2MB h1q slice + 0.4MB meta
// (fits 4MB L2; blockIdx%8->XCD is the round-robin heuristic, perf-only).
// Wave = 8 nodes x 8 lanes (8 int8 ch/lane, uint2 = 1 line/edge). ndesc is
// degree-ASCENDING; read REVERSED (ndesc[N-1-gidx]) so heavy nodes launch first
// and the grid tail drains with light nodes (straggler fix; per-node summation
// order unchanged -> bit-identical). Unroll-4 is the measured local optimum
// (R13: unroll-8 cost occupancy 46->40% and regressed 70->83 us).
__global__ __launch_bounds__(256) void agg1_heads(
    const int2* __restrict__ ndesc, const unsigned short* __restrict__ elist,
    const unsigned char* __restrict__ h1qh, const float2* __restrict__ a1h,
    const float* __restrict__ a1d, const float* __restrict__ b1,
    const float* __restrict__ W2, float* __restrict__ phuf, int N) {
  __shared__ float w2s[256 * 11];  // stride 11 -> conflict-light
  const int t = threadIdx.x;
  for (int i = t; i < 2560; i += 256) {
    int ch = i / 10, jj = i - ch * 10;
    w2s[ch * 11 + jj] = W2[i];
  }

  const int wave = t >> 6, lane = t & 63;
  const int s = lane >> 3;              // node slot in wave: 0..7
  const int k = lane & 7;               // 8 ch per lane: ch = k*8..k*8+7 (in-head)
  const int xcd = blockIdx.x & 7;
  const int head = xcd >> 1, sub = xcd & 1;
  const int chunk = (blockIdx.x >> 3) * 2 + sub;
  const int gidx = chunk * 32 + wave * 8 + s;
  const bool act = gidx < N;
  int2 nd = act ? ndesc[N - 1 - gidx] : make_int2(0, 0);
  const int n = nd.y & 0xFFFF;
  const int row = nd.x;
  const int en = row + (nd.y >> 16);        // includes self-loop
  const float adh = act ? a1d[n * 4 + head] : 0.f;
  const float2* mh = a1h + (size_t)head * N;
  const unsigned char* hb = h1qh + (size_t)head * N * 64 + k * 8;

  float den = 0.f, T = 0.f;
  float acc[8];
#pragma unroll
  for (int u = 0; u < 8; u++) acc[u] = 0.f;

  int j = row;
  for (; j + 4 <= en; j += 4) {
    int ss[4];
    float2 mv[4];
    uint2 qv[4];
#pragma unroll
    for (int u = 0; u < 4; u++) ss[u] = elist[j + u];
#pragma unroll
    for (int u = 0; u < 4; u++) {
      mv[u] = mh[ss[u]];
      qv[u] = *(const uint2*)(hb + ((size_t)ss[u] << 6));
    }
#pragma unroll
    for (int u = 0; u < 4; u++) {
      float l = mv[u].x + adh;
      float e = EXP2(fmaxf(l, NEG_SLOPE * l));
      den += e;
      float se = e * mv[u].y;
      T += se;
      unsigned a = qv[u].x, b = qv[u].y;
      acc[0] = fmaf((float)(a & 0xffu), se, acc[0]);
      acc[1] = fmaf((float)((a >> 8) & 0xffu), se, acc[1]);
      acc[2] = fmaf((float)((a >> 16) & 0xffu), se, acc[2]);
      acc[3] = fmaf((float)(a >> 24), se, acc[3]);
      acc[4] = fmaf((float)(b & 0xffu), se, acc[4]);
      acc[5] = fmaf((float)((b >> 8) & 0xffu), se, acc[5]);
      acc[6] = fmaf((float)((b >> 16) & 0xffu), se, acc[6]);
      acc[7] = fmaf((float)(b >> 24), se, acc[7]);
    }
  }
  for (; j < en; j++) {
    int s0 = elist[j];
    float2 mv = mh[s0];
    uint2 q0 = *(const uint2*)(hb + ((size_t)s0 << 6));
    float l0 = mv.x + adh;
    float e0 = EXP2(fmaxf(l0, NEG_SLOPE * l0));
    den += e0;
    float se = e0 * mv.y;
    T += se;
    unsigned a = q0.x, b = q0.y;
    acc[0] = fmaf((float)(a & 0xffu), se, acc[0]);
    acc[1] = fmaf((float)((a >> 8) & 0xffu), se, acc[1]);
    acc[2] = fmaf((float)((a >> 16) & 0xffu), se, acc[2]);
    acc[3] = fmaf((float)(a >> 24), se, acc[3]);
    acc[4] = fmaf((float)(b & 0xffu), se, acc[4]);
    acc[5] = fmaf((float)((b >> 8) & 0xffu), se, acc[5]);
    acc[6] = fmaf((float)((b >> 16) & 0xffu), se, acc[6]);
    acc[7] = fmaf((float)(b >> 24), se, acc[7]);
  }

  __syncthreads();  // w2s ready (no thread returned early)

  // epilogue: normalize, +bias, ELU, partial GEMM2 over this head's 64 channels
  float bbv[8];
  {
    float4 b0 = *(const float4*)(b1 + head * 64 + k * 8);
    float4 b1v = *(const float4*)(b1 + head * 64 + k * 8 + 4);
    bbv[0] = b0.x; bbv[1] = b0.y; bbv[2] = b0.z; bbv[3] = b0.w;
    bbv[4] = b1v.x; bbv[5] = b1v.y; bbv[6] = b1v.z; bbv[7] = b1v.w;
  }
  float inv = act ? 1.0f / den : 0.f;
  float corr = 128.0f * T;
  float pv[10];
#pragma unroll
  for (int jj = 0; jj < 10; jj++) pv[jj] = 0.f;
#pragma unroll
  for (int u = 0; u < 8; u++) {
    float c = (acc[u] - corr) * inv + bbv[u];
    c = c > 0.f ? c : expm1f(c);
    const float* wrow = w2s + (head * 64 + k * 8 + u) * 11;
#pragma unroll
    for (int jj = 0; jj < 10; jj++) pv[jj] = fmaf(c, wrow[jj], pv[jj]);
  }
#pragma unroll
  for (int off = 4; off > 0; off >>= 1) {
#pragma unroll
    for (int jj = 0; jj < 10; jj++) pv[jj] += __shfl_down(pv[jj], off, 8);
  }
  if (act && k == 0) {
    float* pp = phuf + ((size_t)n * 4 + head) * 10;
#pragma unroll
    for (int jj = 0; jj < 10; jj++) pp[jj] = pv[jj];
  }
}

// ---------------- combine: sum 4 head-partials -> h2 (fp16) + att2 tails ----------
__global__ __launch_bounds__(256) void combine(
    const float* __restrict__ phuf, const float* __restrict__ as2,
    const float* __restrict__ ad2, __half* __restrict__ h2, int N) {
  int n = blockIdx.x * 256 + threadIdx.x;
  if (n >= N) return;
  const float* pp = phuf + (size_t)n * 40;
  float ds = 0.f, dd = 0.f;
#pragma unroll
  for (int jj = 0; jj < 10; jj++) {
    float p = pp[jj] + pp[10 + jj] + pp[20 + jj] + pp[30 + jj];
    h2[(size_t)n * 16 + jj] = __float2half(p);
    ds = fmaf(p, as2[jj], ds);
    dd = fmaf(p, ad2[jj], dd);
  }
  float* ft = (float*)(h2 + (size_t)n * 16);
  ft[5] = ds * LOG2E;   // a2s in h2 row tail
  ft[6] = dd * LOG2E;   // a2d
}

// ---------------- agg2: wave-per-node, 12 groups x 5 lanes (half2 = 2 channels).
// a2s/a2d read from the h2 row tail -> exactly ONE 64B line per edge; u16 elist. --
__global__ __launch_bounds__(256) void agg2_csr(
    const int* __restrict__ rowptr, const unsigned short* __restrict__ elist,
    const __half* __restrict__ h2, const float* __restrict__ b2,
    float* __restrict__ out, int N) {
  int wave = threadIdx.x >> 6, lane = threadIdx.x & 63;
  int n = blockIdx.x * 4 + wave;
  if (n >= N) return;
  int row = rowptr[n];
  int deg = rowptr[n + 1] - row;
  const unsigned short* el = elist + row;
  const float* hf = (const float*)h2;
  float ad = hf[(size_t)n * 8 + 6];  // pre-scaled a2d from own row tail
  int g = lane / 5;      // 0..11 active, lanes 60-63 idle (g=12)
  int c2 = lane - g * 5; // channel-pair index 0..4
  float den = 0.f, ax = 0.f, ay = 0.f;
  if (g < 12) {
    int jj = g;
    for (; jj + 12 < deg; jj += 24) {
      int sA = el[jj], sB = el[jj + 12];
      float lA = hf[(size_t)sA * 8 + 5] + ad;
      float lB = hf[(size_t)sB * 8 + 5] + ad;
      __half2 hA = *(const __half2*)(h2 + (size_t)sA * 16 + c2 * 2);
      __half2 hB = *(const __half2*)(h2 + (size_t)sB * 16 + c2 * 2);
      float eA = EXP2(fmaxf(lA, NEG_SLOPE * lA));
      float eB = EXP2(fmaxf(lB, NEG_SLOPE * lB));
      den += eA + eB;
      float2 fA = __half22float2(hA);
      float2 fB = __half22float2(hB);
      ax = fmaf(eA, fA.x, fmaf(eB, fB.x, ax));
      ay = fmaf(eA, fA.y, fmaf(eB, fB.y, ay));
    }
    for (; jj < deg; jj += 12) {
      int s = el[jj];
      float l = hf[(size_t)s * 8 + 5] + ad;
      __half2 hv = *(const __half2*)(h2 + (size_t)s * 16 + c2 * 2);
      float ev = EXP2(fmaxf(l, NEG_SLOPE * l));
      den += ev;
      float2 f = __half22float2(hv);
      ax = fmaf(ev, f.x, ax);
      ay = fmaf(ev, f.y, ay);
    }
  }
  // reduce the 12 stride-5 groups: +30 (g+6), then +10/+20 (g+2,g+4), then +5 (g+1)
  ax += __shfl_down(ax, 30, 64);
  ay += __shfl_down(ay, 30, 64);
  den += __shfl_down(den, 30, 64);
  ax += __shfl_down(ax, 10, 64) + __shfl_down(ax, 20, 64);
  ay += __shfl_down(ay, 10, 64) + __shfl_down(ay, 20, 64);
  den += __shfl_down(den, 10, 64) + __shfl_down(den, 20, 64);
  ax += __shfl_down(ax, 5, 64);
  ay += __shfl_down(ay, 5, 64);
  den += __shfl_down(den, 5, 64);
  if (lane < 5) {
    float inv = 1.0f / den;
    float2 bb = *(const float2*)(b2 + lane * 2);
    float2 o = make_float2(fmaf(ax, inv, bb.x), fmaf(ay, inv, bb.y));
    *(float2*)(out + (size_t)n * 10 + lane * 2) = o;
  }
}

extern "C" void kernel_launch(void* const* d_in, const int* in_sizes, int n_in,
                              void* d_out, int out_size, void* d_ws, size_t ws_size,
                              hipStream_t stream) {
  const float* x = (const float*)d_in[0];
  const int* ei = (const int*)d_in[1];
  const float* W1 = (const float*)d_in[2];
  const float* as1 = (const float*)d_in[3];
  const float* ad1 = (const float*)d_in[4];
  const float* b1 = (const float*)d_in[5];
  const float* W2 = (const float*)d_in[6];
  const float* as2 = (const float*)d_in[7];
  const float* ad2 = (const float*)d_in[8];
  const float* b2 = (const float*)d_in[9];
  float* out = (float*)d_out;

  const int N = in_sizes[0] / 128;   // 50000
  const int E = in_sizes[1] / 2;     // 800000
  const int* srcp = ei;
  const int* dstp = ei + E;

  char* ws = (char*)d_ws;
  size_t off = 0;
  auto alloc = [&](size_t nbytes) {
    char* p = ws + off;
    off += (nbytes + 255) & ~(size_t)255;
    return p;
  };
  unsigned char* h1qh = (unsigned char*)alloc((size_t)N * 256);  // [4][N][64]
  float2* a1h = (float2*)alloc((size_t)N * 4 * 8);               // [4][N]{a1s,hscale}
  half8* Bpack = (half8*)alloc((size_t)4096 * 16);
  float* a1d = (float*)alloc((size_t)N * 4 * 4);
  float* phuf = (float*)alloc((size_t)N * 40 * 4);               // [N][4][10]
  __half* h2 = (__half*)alloc((size_t)N * 16 * 2);
  int* zbuf = (int*)alloc((size_t)(N + 8192) * 4);  // deg[N] ++ binCnt pad ++ cursor pad
  int* deg = zbuf;
  int* binCnt = zbuf + N;          // [256] stride-16 (64B line each)
  int* cursor = zbuf + N + 4096;   // [256] stride-16
  int* excl = (int*)alloc((size_t)N * 4);
  int* bsum = (int*)alloc(256 * 4);
  int* rowptr = (int*)alloc((size_t)(N + 1) * 4);
  int2* ndesc = (int2*)alloc((size_t)N * 8);
  int* rank = (int*)alloc((size_t)E * 4);
  unsigned short* elist = (unsigned short*)alloc((size_t)(E + (size_t)N) * 2);

  const int nb = (N + 255) / 256;          // 196
  const int nbz = (N + 8192 + 255) / 256;
  const int gemmBlocks = (N / 16 + 3) / 4; // 782
  const int histBlocks = 512;
  const int scatB = (E + 255) / 256;       // 3125
  const int chunks = (N + 31) / 32;        // 1563 (32 nodes per block per head)
  const int hgrid = ((chunks + 1) / 2) * 8;

  // L1: pack W1 + zero deg/binCnt/cursor
  prep1<<<16 + nbz, 256, 0, stream>>>(W1, Bpack, zbuf, N);
  // L2: gemm1 (MFMA -> per-head int8 slices + per-head meta, att dots) || hist+rank
  phase2<<<gemmBlocks + histBlocks, 256, 0, stream>>>(
      x, Bpack, as1, ad1, h1qh, a1h, a1d, dstp, deg, rank, N, E,
      gemmBlocks, histBlocks);
  // CSR: scan (+LDS deg-hist), then {rowptr+selfloops ∥ binscan}, then
  // {scatter ∥ place+ndesc} — 3 launches total for the whole CSR/sort chain
  scan_local<<<nb, 256, 0, stream>>>(deg, excl, bsum, binCnt, N);
  scan_add2<<<nb + 1, 256, 0, stream>>>(excl, bsum, binCnt, cursor, rowptr, elist,
                                        N, nb);
  scatter_place<<<scatB + nb, 256, 0, stream>>>(srcp, dstp, rank, rowptr, deg,
                                                cursor, elist, ndesc, E, N, scatB);
  // layer 1 aggregate, head-sliced per XCD pair (+ per-head partial GEMM2)
  agg1_heads<<<hgrid, 256, 0, stream>>>(ndesc, elist, h1qh, a1h, a1d,
                                        b1, W2, phuf, N);
  // sum head partials -> h2 + att2 tails
  combine<<<(N + 255) / 256, 256, 0, stream>>>(phuf, as2, ad2, h2, N);
  // layer 2 aggregate
  agg2_csr<<<(N + 3) / 4, 256, 0, stream>>>(rowptr, elist, h2, b2, out, N);
}